// Round 7
// baseline (633.398 us; speedup 1.0000x reference)
//
#include <hip/hip_runtime.h>

typedef __bf16 bf16_t;
typedef __bf16 bf16x8 __attribute__((ext_vector_type(8)));
typedef __bf16 bf16x4 __attribute__((ext_vector_type(4)));
typedef float  f32x4  __attribute__((ext_vector_type(4)));

#define MFMA16(a,b,c) __builtin_amdgcn_mfma_f32_16x16x32_bf16((a),(b),(c),0,0,0)

// ---------- LDS helpers with XOR swizzle (byte ^= (row&7)<<4) ----------
__device__ __forceinline__ bf16x8 lds_read8(const bf16_t* base, int row, int k, int rowB) {
    int byte = row * rowB + (k << 1);
    byte ^= ((row & 7) << 4);
    return *(const bf16x8*)((const char*)base + byte);
}
__device__ __forceinline__ void lds_write8B(bf16_t* base, int row, int col, int rowB, bf16x4 v) {
    int byte = row * rowB + (col << 1);
    byte ^= ((row & 7) << 4);
    *(bf16x4*)((char*)base + byte) = v;
}
__device__ __forceinline__ bf16x4 lds_read8B(const bf16_t* base, int row, int col, int rowB) {
    int byte = row * rowB + (col << 1);
    byte ^= ((row & 7) << 4);
    return *(const bf16x4*)((const char*)base + byte);
}
__device__ __forceinline__ void lds_write1(bf16_t* base, int row, int col, int rowB, float v) {
    int byte = row * rowB + (col << 1);
    byte ^= ((row & 7) << 4);
    *(bf16_t*)((char*)base + byte) = (bf16_t)v;
}
__device__ __forceinline__ void lds_write16B(bf16_t* base, int row, int colbyte, int rowB, bf16x8 v) {
    int byte = row * rowB + colbyte;
    byte ^= ((row & 7) << 4);
    *(bf16x8*)((char*)base + byte) = v;
}
__device__ __forceinline__ bf16x8 lds_read16B(const bf16_t* base, int row, int colbyte, int rowB) {
    int byte = row * rowB + colbyte;
    byte ^= ((row & 7) << 4);
    return *(const bf16x8*)((const char*)base + byte);
}

// ---------- 128-row block GEMM: wave tile 64 rows x 128 cols ----------
// SWAPPED operands: MFMA16(b, a, acc) -> C[row = rf*16+l15][col = n0+cf*16+lhi*4+r]
template<int K>
__device__ __forceinline__ void gemm_w(f32x4 (&acc)[4][8],
    const bf16_t* act, int rowB, const bf16_t* __restrict__ W,
    int n0, int wm, int l15, int lhi)
{
    constexpr int NS = K / 32;
    const bf16_t* wp = W + (size_t)(n0 + l15) * K + lhi * 8;
#pragma unroll
    for (int s = 0; s < NS; ++s) {
        bf16x8 a[4], b[8];
#pragma unroll
        for (int cf = 0; cf < 8; ++cf)
            b[cf] = *(const bf16x8*)(wp + (size_t)cf * 16 * K + s * 32);
#pragma unroll
        for (int rf = 0; rf < 4; ++rf)
            a[rf] = lds_read8(act, wm * 64 + rf * 16 + l15, s * 32 + lhi * 8, rowB);
#pragma unroll
        for (int rf = 0; rf < 4; ++rf)
#pragma unroll
            for (int cf = 0; cf < 8; ++cf)
                acc[rf][cf] = MFMA16(b[cf], a[rf], acc[rf][cf]);
    }
}

__device__ __forceinline__ void zero_acc(f32x4 (&acc)[4][8]) {
#pragma unroll
    for (int rf = 0; rf < 4; ++rf)
#pragma unroll
        for (int cf = 0; cf < 8; ++cf)
            acc[rf][cf] = f32x4{0.f, 0.f, 0.f, 0.f};
}

// epilogue into in-place act buffer (after barrier)
template<bool RELU>
__device__ __forceinline__ void epi_act(const f32x4 (&acc)[4][8], const float* __restrict__ bias,
    bf16_t* act, int n0, int wm, int l15, int lhi)
{
#pragma unroll
    for (int cf = 0; cf < 8; ++cf) {
        const int c0 = n0 + cf * 16 + lhi * 4;
        float4 b4 = *(const float4*)(bias + c0);
#pragma unroll
        for (int rf = 0; rf < 4; ++rf) {
            float v0 = acc[rf][cf][0] + b4.x;
            float v1 = acc[rf][cf][1] + b4.y;
            float v2 = acc[rf][cf][2] + b4.z;
            float v3 = acc[rf][cf][3] + b4.w;
            if (RELU) {
                v0 = fmaxf(v0, 0.f); v1 = fmaxf(v1, 0.f);
                v2 = fmaxf(v2, 0.f); v3 = fmaxf(v3, 0.f);
            }
            bf16x4 p = { (bf16_t)v0, (bf16_t)v1, (bf16_t)v2, (bf16_t)v3 };
            lds_write8B(act, wm * 64 + rf * 16 + l15, c0, 1024, p);
        }
    }
}

__device__ __forceinline__ void epi_out_nt(const f32x4 (&acc)[4][8], const float* __restrict__ bias,
    float* __restrict__ out, long r0, int n0, int wm, int l15, int lhi)
{
#pragma unroll
    for (int cf = 0; cf < 8; ++cf) {
        const int c0 = n0 + cf * 16 + lhi * 4;
        float4 b4 = *(const float4*)(bias + c0);
#pragma unroll
        for (int rf = 0; rf < 4; ++rf) {
            f32x4 o = { acc[rf][cf][0] + b4.x, acc[rf][cf][1] + b4.y,
                        acc[rf][cf][2] + b4.z, acc[rf][cf][3] + b4.w };
            __builtin_nontemporal_store(o,
                (f32x4*)(out + (r0 + wm * 64 + rf * 16 + l15) * 512 + c0));
        }
    }
}

// ---------- kernel 1: cast all weights to bf16 into ws ----------
__global__ __launch_bounds__(256) void cast_kernel(
    const float* __restrict__ W1, const float* __restrict__ W2,
    const float* __restrict__ muW, const float* __restrict__ lvW,
    const float* __restrict__ Wqkv, const float* __restrict__ Wo,
    const float* __restrict__ Wc, const float* __restrict__ Wd1,
    const float* __restrict__ Wd2, const float* __restrict__ Wd3,
    bf16_t* __restrict__ dst)
{
    int i = blockIdx.x * 256 + threadIdx.x;   // grid exactly covers 1376256
    const float* src; int off;
    if      (i <  262144) { src = W1;   off = 0; }
    else if (i <  524288) { src = W2;   off = 262144; }
    else if (i <  655360) { src = muW;  off = 524288; }
    else if (i <  786432) { src = lvW;  off = 655360; }
    else if (i <  798720) { src = Wqkv; off = 786432; }
    else if (i <  802816) { src = Wo;   off = 798720; }
    else if (i <  819200) { src = Wc;   off = 802816; }
    else if (i <  851968) { src = Wd1;  off = 819200; }
    else if (i < 1114112) { src = Wd2;  off = 851968; }
    else                  { src = Wd3;  off = 1114112; }
    dst[i] = (bf16_t)src[i - off];
}

// ---------- kernel 2: encoder + heads + reparameterize (128-row blocks) ----------
__global__ __launch_bounds__(512, 2) void enc_kernel(
    const float* __restrict__ x, const float* __restrict__ eps,
    const bf16_t* __restrict__ W1b, const float* __restrict__ b1,
    const bf16_t* __restrict__ W2b, const float* __restrict__ b2,
    const bf16_t* __restrict__ Hb,  const float* __restrict__ mub,
    const float* __restrict__ lvb,  bf16_t* __restrict__ zout)
{
    __shared__ bf16_t act[128 * 512];   // 128 KB, in-place across layers
    const int t = threadIdx.x;
    const int wave = t >> 6, lane = t & 63, l15 = lane & 15, lhi = lane >> 4;
    const int wm = wave >> 2, wn = wave & 3, n0 = wn * 128;
    const size_t r0 = (size_t)blockIdx.x * 128;

    // stage x tile (fp32 -> bf16, swizzled); nt loads (read-once stream)
    for (int it = 0; it < 32; ++it) {
        int flat = it * 512 + t;
        int row = flat >> 7, c4 = flat & 127;
        f32x4 v = __builtin_nontemporal_load(
            (const f32x4*)(x + (r0 + row) * 512 + c4 * 4));
        bf16x4 h = { (bf16_t)v[0], (bf16_t)v[1], (bf16_t)v[2], (bf16_t)v[3] };
        int byte = (row << 10) + (c4 << 3);
        byte ^= ((row & 7) << 4);
        *(bf16x4*)((char*)act + byte) = h;
    }
    __syncthreads();

    f32x4 acc[4][8];
    {   // layer 1
        zero_acc(acc);
        gemm_w<512>(acc, act, 1024, W1b, n0, wm, l15, lhi);
        __syncthreads();
        epi_act<true>(acc, b1, act, n0, wm, l15, lhi);
        __syncthreads();
    }
    {   // layer 2
        zero_acc(acc);
        gemm_w<512>(acc, act, 1024, W2b, n0, wm, l15, lhi);
        __syncthreads();
        epi_act<true>(acc, b2, act, n0, wm, l15, lhi);
        __syncthreads();
    }
    {   // heads: cols 0-255 mu, 256-511 lv
        zero_acc(acc);
        gemm_w<512>(acc, act, 1024, Hb, n0, wm, l15, lhi);
        __syncthreads();
        epi_act<false>(acc, (n0 < 256) ? mub : (lvb - 256), act, n0, wm, l15, lhi);
        __syncthreads();
    }

    // z = mu + eps * T^1.5 * exp(0.5*lv); mu cols 0-255, lv cols 256-511
    const int cc = (t & 63) * 4;
    const int ag = cc >> 6;
    const float tp = (ag == 0) ? 1.8371173070873836f
                   : (ag == 1) ? 0.35355339059327373f
                   : (ag == 2) ? 1.0f
                               : 0.7155417527999327f;
    const int rb = t >> 6;
    for (int it = 0; it < 16; ++it) {
        int row = it * 8 + rb;
        bf16x4 mu4 = lds_read8B(act, row, cc, 1024);
        bf16x4 lv4 = lds_read8B(act, row, cc + 256, 1024);
        f32x4 ep4 = __builtin_nontemporal_load(
            (const f32x4*)(eps + (r0 + row) * 256 + cc));
        bf16x4 zo;
        zo[0] = (bf16_t)fmaf(ep4[0] * tp, expf(0.5f * (float)lv4[0]), (float)mu4[0]);
        zo[1] = (bf16_t)fmaf(ep4[1] * tp, expf(0.5f * (float)lv4[1]), (float)mu4[1]);
        zo[2] = (bf16_t)fmaf(ep4[2] * tp, expf(0.5f * (float)lv4[2]), (float)mu4[2]);
        zo[3] = (bf16_t)fmaf(ep4[3] * tp, expf(0.5f * (float)lv4[3]), (float)mu4[3]);
        *(bf16x4*)(zout + (r0 + row) * 256 + cc) = zo;
    }
}

// ---------- kernel 3: attention over 4 agents + consensus (unchanged) ----------
__global__ __launch_bounds__(512) void attn_kernel(
    const bf16_t* __restrict__ z,
    const bf16_t* __restrict__ Wqkvb, const float* __restrict__ bqkv,
    const bf16_t* __restrict__ Wob,   const float* __restrict__ bo,
    const bf16_t* __restrict__ Wcb,   const float* __restrict__ bc,
    bf16_t* __restrict__ zcb)
{
    __shared__ bf16_t zt[256 * 64];    // z tile, later ctx tile   (rowB 128)
    __shared__ bf16_t qt[256 * 192];   // qkv tile, later z_att    (rowB 384/128)
    const int t = threadIdx.x;
    const size_t s0 = (size_t)blockIdx.x * 64;

    for (int it = 0; it < 4; ++it) {
        int ch = it * 512 + t;
        int r = ch >> 3, cc = ch & 7;
        bf16x8 v = *(const bf16x8*)(z + s0 * 256 + r * 64 + cc * 8);
        lds_write16B(zt, r, cc * 16, 128, v);
    }
    __syncthreads();
    const int wave = t >> 6, lane = t & 63, l15 = lane & 15, lhi = lane >> 4;
    const int rbase = wave * 32;

    for (int cc = 0; cc < 4; ++cc) {
        f32x4 acc[2][3] = {};
#pragma unroll
        for (int ks = 0; ks < 2; ++ks) {
            int k = ks * 32 + lhi * 8;
            bf16x8 a0 = lds_read8(zt, rbase + l15, k, 128);
            bf16x8 a1 = lds_read8(zt, rbase + 16 + l15, k, 128);
#pragma unroll
            for (int cf = 0; cf < 3; ++cf) {
                bf16x8 b = *(const bf16x8*)(Wqkvb + (cc * 48 + cf * 16 + l15) * 64 + k);
                acc[0][cf] = MFMA16(a0, b, acc[0][cf]);
                acc[1][cf] = MFMA16(a1, b, acc[1][cf]);
            }
        }
#pragma unroll
        for (int cf = 0; cf < 3; ++cf) {
            int col = cc * 48 + cf * 16 + l15;
            float bs = bqkv[col];
#pragma unroll
            for (int rf = 0; rf < 2; ++rf)
#pragma unroll
                for (int r = 0; r < 4; ++r)
                    lds_write1(qt, rbase + rf * 16 + lhi * 4 + r, col, 384, acc[rf][cf][r] + bs);
        }
    }
    __syncthreads();

    if (t < 256) {
        const int sl = t >> 2, head = t & 3;
        bf16x8 qv[4][2], kv[4][2], vv[4][2];
#pragma unroll
        for (int a2 = 0; a2 < 4; ++a2) {
            int r = sl * 4 + a2;
#pragma unroll
            for (int i = 0; i < 2; ++i) {
                qv[a2][i] = lds_read16B(qt, r, head * 32 + 16 * i, 384);
                kv[a2][i] = lds_read16B(qt, r, 128 + head * 32 + 16 * i, 384);
                vv[a2][i] = lds_read16B(qt, r, 256 + head * 32 + 16 * i, 384);
            }
        }
        float sc[4][4];
#pragma unroll
        for (int qa = 0; qa < 4; ++qa)
#pragma unroll
            for (int ka = 0; ka < 4; ++ka) {
                float s = 0.f;
#pragma unroll
                for (int i = 0; i < 2; ++i)
#pragma unroll
                    for (int j = 0; j < 8; ++j)
                        s += (float)qv[qa][i][j] * (float)kv[ka][i][j];
                sc[qa][ka] = s * 0.25f;
            }
#pragma unroll
        for (int qa = 0; qa < 4; ++qa) {
            float m = fmaxf(fmaxf(sc[qa][0], sc[qa][1]), fmaxf(sc[qa][2], sc[qa][3]));
            float e[4], sum = 0.f;
#pragma unroll
            for (int ka = 0; ka < 4; ++ka) { e[ka] = expf(sc[qa][ka] - m); sum += e[ka]; }
            float inv = 1.f / sum;
#pragma unroll
            for (int i = 0; i < 2; ++i) {
                bf16x8 cv;
#pragma unroll
                for (int j = 0; j < 8; ++j) {
                    float cval = 0.f;
#pragma unroll
                    for (int ka = 0; ka < 4; ++ka) cval += e[ka] * inv * (float)vv[ka][i][j];
                    cv[j] = (bf16_t)cval;
                }
                lds_write16B(zt, sl * 4 + qa, head * 32 + 16 * i, 128, cv);
            }
        }
    }
    __syncthreads();

    {   // z_att = ctx @ Wo^T + bo
        f32x4 acc[2][4] = {};
#pragma unroll
        for (int ks = 0; ks < 2; ++ks) {
            int k = ks * 32 + lhi * 8;
            bf16x8 a0 = lds_read8(zt, rbase + l15, k, 128);
            bf16x8 a1 = lds_read8(zt, rbase + 16 + l15, k, 128);
#pragma unroll
            for (int cf = 0; cf < 4; ++cf) {
                bf16x8 b = *(const bf16x8*)(Wob + (cf * 16 + l15) * 64 + k);
                acc[0][cf] = MFMA16(a0, b, acc[0][cf]);
                acc[1][cf] = MFMA16(a1, b, acc[1][cf]);
            }
        }
        __syncthreads();
#pragma unroll
        for (int cf = 0; cf < 4; ++cf) {
            int col = cf * 16 + l15;
            float bs = bo[col];
#pragma unroll
            for (int rf = 0; rf < 2; ++rf)
#pragma unroll
                for (int r = 0; r < 4; ++r)
                    lds_write1(qt, rbase + rf * 16 + lhi * 4 + r, col, 128, acc[rf][cf][r] + bs);
        }
    }
    __syncthreads();

    {   // z_consensus = z_att.reshape(64,256) @ Wc^T + bc
        f32x4 acc2[2] = {};
        const int rfw = wave >> 1, cbase = (wave & 1) * 2;
        const int srow = rfw * 16 + l15;
#pragma unroll
        for (int ks = 0; ks < 8; ++ks) {
            int k = ks * 32 + lhi * 8;
            int byte = (srow << 9) + (k << 1);
            byte ^= ((((srow << 2) + (k >> 6)) & 7) << 4);
            bf16x8 a = *(const bf16x8*)((const char*)qt + byte);
#pragma unroll
            for (int i = 0; i < 2; ++i) {
                bf16x8 b = *(const bf16x8*)(Wcb + ((cbase + i) * 16 + l15) * 256 + k);
                acc2[i] = MFMA16(a, b, acc2[i]);
            }
        }
#pragma unroll
        for (int i = 0; i < 2; ++i) {
            int col = (cbase + i) * 16 + l15;
            float bs = bc[col];
#pragma unroll
            for (int r = 0; r < 4; ++r) {
                int s = (int)(s0) + rfw * 16 + lhi * 4 + r;
                zcb[(size_t)s * 64 + col] = (bf16_t)(acc2[i][r] + bs);
            }
        }
    }
}

// ---------- kernel 4: fused 3-layer decoder (128-row blocks, nt streams) ----------
__global__ __launch_bounds__(512, 2) void dec_kernel(
    const bf16_t* __restrict__ z, const bf16_t* __restrict__ zc,
    const bf16_t* __restrict__ Wd1b, const float* __restrict__ bd1,
    const bf16_t* __restrict__ Wd2b, const float* __restrict__ bd2,
    const bf16_t* __restrict__ Wd3b, const float* __restrict__ bd3,
    float* __restrict__ out)
{
    __shared__ bf16_t zz[128 * 64];     // 16 KB latent tile (rowB 128)
    __shared__ bf16_t act[128 * 512];   // 128 KB, in-place across layers
    const int t = threadIdx.x;
    const int wave = t >> 6, lane = t & 63, l15 = lane & 15, lhi = lane >> 4;
    const int wm = wave >> 2, wn = wave & 3, n0 = wn * 128;
    const long r0 = (long)blockIdx.x * 128;

    // gather latent rows (nt: read-once stream): row = s*5 + j
    for (int it = 0; it < 2; ++it) {
        int flat = it * 512 + t;
        int row = flat >> 3, ch = flat & 7;
        long rg = r0 + row;
        int s5 = (int)(rg / 5), j = (int)(rg - (long)s5 * 5);
        const bf16_t* src = (j == 0) ? (zc + (size_t)s5 * 64)
                                     : (z + (size_t)s5 * 256 + (j - 1) * 64);
        bf16x8 v = __builtin_nontemporal_load((const bf16x8*)(src + ch * 8));
        int byte = (row << 7) + (ch << 4);
        byte ^= ((row & 7) << 4);
        *(bf16x8*)((char*)zz + byte) = v;
    }
    __syncthreads();

    f32x4 acc[4][8];
    {   // layer 1: K=64 from zz
        zero_acc(acc);
        gemm_w<64>(acc, zz, 128, Wd1b, n0, wm, l15, lhi);
        // no barrier needed before epi: act not yet read
        epi_act<true>(acc, bd1, act, n0, wm, l15, lhi);
        __syncthreads();
    }
    {   // layer 2 (in-place)
        zero_acc(acc);
        gemm_w<512>(acc, act, 1024, Wd2b, n0, wm, l15, lhi);
        __syncthreads();
        epi_act<true>(acc, bd2, act, n0, wm, l15, lhi);
        __syncthreads();
    }
    {   // layer 3 -> global fp32 (nt float4 stores)
        zero_acc(acc);
        gemm_w<512>(acc, act, 1024, Wd3b, n0, wm, l15, lhi);
        epi_out_nt(acc, bd3, out, r0, n0, wm, l15, lhi);
    }
}

// ---------- launcher ----------
extern "C" void kernel_launch(void* const* d_in, const int* in_sizes, int n_in,
                              void* d_out, int out_size, void* d_ws, size_t ws_size,
                              hipStream_t stream) {
    const float* x    = (const float*)d_in[0];
    const float* eps  = (const float*)d_in[1];
    const float* W1   = (const float*)d_in[2];
    const float* b1   = (const float*)d_in[3];
    const float* W2   = (const float*)d_in[4];
    const float* b2   = (const float*)d_in[5];
    const float* muW  = (const float*)d_in[6];
    const float* mub  = (const float*)d_in[7];
    const float* lvW  = (const float*)d_in[8];
    const float* lvb  = (const float*)d_in[9];
    const float* Wqkv = (const float*)d_in[10];
    const float* bqkv = (const float*)d_in[11];
    const float* Wo   = (const float*)d_in[12];
    const float* bo   = (const float*)d_in[13];
    const float* Wc   = (const float*)d_in[14];
    const float* bc   = (const float*)d_in[15];
    const float* Wd1  = (const float*)d_in[16];
    const float* bd1  = (const float*)d_in[17];
    const float* Wd2  = (const float*)d_in[18];
    const float* bd2  = (const float*)d_in[19];
    const float* Wd3  = (const float*)d_in[20];
    const float* bd3  = (const float*)d_in[21];
    float* out = (float*)d_out;

    bf16_t* wsb  = (bf16_t*)d_ws;
    bf16_t* W1b  = wsb + 0;
    bf16_t* W2b  = wsb + 262144;
    bf16_t* Hb   = wsb + 524288;    // [muW(256x512) ; lvW(256x512)]
    bf16_t* Wqkvb= wsb + 786432;
    bf16_t* Wob  = wsb + 798720;
    bf16_t* Wcb  = wsb + 802816;
    bf16_t* Wd1b = wsb + 819200;
    bf16_t* Wd2b = wsb + 851968;
    bf16_t* Wd3b = wsb + 1114112;
    bf16_t* zbuf = wsb + 1376256;   // (B,256) bf16
    bf16_t* zcb  = wsb + 9764864;   // (B,64)  bf16

    cast_kernel<<<dim3(5376), dim3(256), 0, stream>>>(
        W1, W2, muW, lvW, Wqkv, Wo, Wc, Wd1, Wd2, Wd3, wsb);
    enc_kernel<<<dim3(256), dim3(512), 0, stream>>>(
        x, eps, W1b, b1, W2b, b2, Hb, mub, lvb, zbuf);
    attn_kernel<<<dim3(512), dim3(512), 0, stream>>>(
        zbuf, Wqkvb, bqkv, Wob, bo, Wcb, bc, zcb);
    dec_kernel<<<dim3(1280), dim3(512), 0, stream>>>(
        zbuf, zcb, Wd1b, bd1, Wd2b, bd2, Wd3b, bd3, out);
}

// Round 8
// 608.524 us; speedup vs baseline: 1.0409x; 1.0409x over previous
//
#include <hip/hip_runtime.h>

typedef __bf16 bf16_t;
typedef __bf16 bf16x8 __attribute__((ext_vector_type(8)));
typedef __bf16 bf16x4 __attribute__((ext_vector_type(4)));
typedef float  f32x4  __attribute__((ext_vector_type(4)));

#define MFMA16(a,b,c) __builtin_amdgcn_mfma_f32_16x16x32_bf16((a),(b),(c),0,0,0)

// ---------- LDS helpers with XOR swizzle (byte ^= (row&7)<<4) ----------
__device__ __forceinline__ bf16x8 lds_read8(const bf16_t* base, int row, int k, int rowB) {
    int byte = row * rowB + (k << 1);
    byte ^= ((row & 7) << 4);
    return *(const bf16x8*)((const char*)base + byte);
}
__device__ __forceinline__ void lds_write8B(bf16_t* base, int row, int col, int rowB, bf16x4 v) {
    int byte = row * rowB + (col << 1);
    byte ^= ((row & 7) << 4);
    *(bf16x4*)((char*)base + byte) = v;
}
__device__ __forceinline__ bf16x4 lds_read8B(const bf16_t* base, int row, int col, int rowB) {
    int byte = row * rowB + (col << 1);
    byte ^= ((row & 7) << 4);
    return *(const bf16x4*)((const char*)base + byte);
}
__device__ __forceinline__ void lds_write1(bf16_t* base, int row, int col, int rowB, float v) {
    int byte = row * rowB + (col << 1);
    byte ^= ((row & 7) << 4);
    *(bf16_t*)((char*)base + byte) = (bf16_t)v;
}
__device__ __forceinline__ void lds_write16B(bf16_t* base, int row, int colbyte, int rowB, bf16x8 v) {
    int byte = row * rowB + colbyte;
    byte ^= ((row & 7) << 4);
    *(bf16x8*)((char*)base + byte) = v;
}
__device__ __forceinline__ bf16x8 lds_read16B(const bf16_t* base, int row, int colbyte, int rowB) {
    int byte = row * rowB + colbyte;
    byte ^= ((row & 7) << 4);
    return *(const bf16x8*)((const char*)base + byte);
}

// ---------- wave tile 128 rows x 64 cols (acc[8][4]), K-step 32 ----------
// SWAPPED operands: MFMA16(b, a, acc) -> C[row = rf*16+l15][col = n0+cf*16+lhi*4+r]
// All 8 waves read the same 128-row act tile; each owns a 64-col slice of W.
template<int K>
__device__ __forceinline__ void gemm_w128(f32x4 (&acc)[8][4],
    const bf16_t* act, int rowB, const bf16_t* __restrict__ W,
    int n0, int l15, int lhi)
{
    constexpr int NS = K / 32;
    const bf16_t* wp = W + (size_t)(n0 + l15) * K + lhi * 8;
#pragma unroll
    for (int s = 0; s < NS; ++s) {
        bf16x8 b[4], a[8];
#pragma unroll
        for (int cf = 0; cf < 4; ++cf)
            b[cf] = *(const bf16x8*)(wp + (size_t)cf * 16 * K + s * 32);
#pragma unroll
        for (int rf = 0; rf < 8; ++rf)
            a[rf] = lds_read8(act, rf * 16 + l15, s * 32 + lhi * 8, rowB);
#pragma unroll
        for (int rf = 0; rf < 8; ++rf)
#pragma unroll
            for (int cf = 0; cf < 4; ++cf)
                acc[rf][cf] = MFMA16(b[cf], a[rf], acc[rf][cf]);
    }
}

__device__ __forceinline__ void zero_acc(f32x4 (&acc)[8][4]) {
#pragma unroll
    for (int rf = 0; rf < 8; ++rf)
#pragma unroll
        for (int cf = 0; cf < 4; ++cf)
            acc[rf][cf] = f32x4{0.f, 0.f, 0.f, 0.f};
}

template<bool RELU>
__device__ __forceinline__ void epi_act(const f32x4 (&acc)[8][4], const float* __restrict__ bias,
    bf16_t* act, int n0, int l15, int lhi)
{
#pragma unroll
    for (int cf = 0; cf < 4; ++cf) {
        const int c0 = n0 + cf * 16 + lhi * 4;
        float4 b4 = *(const float4*)(bias + c0);
#pragma unroll
        for (int rf = 0; rf < 8; ++rf) {
            float v0 = acc[rf][cf][0] + b4.x;
            float v1 = acc[rf][cf][1] + b4.y;
            float v2 = acc[rf][cf][2] + b4.z;
            float v3 = acc[rf][cf][3] + b4.w;
            if (RELU) {
                v0 = fmaxf(v0, 0.f); v1 = fmaxf(v1, 0.f);
                v2 = fmaxf(v2, 0.f); v3 = fmaxf(v3, 0.f);
            }
            bf16x4 p = { (bf16_t)v0, (bf16_t)v1, (bf16_t)v2, (bf16_t)v3 };
            lds_write8B(act, rf * 16 + l15, c0, 1024, p);
        }
    }
}

__device__ __forceinline__ void epi_out(const f32x4 (&acc)[8][4], const float* __restrict__ bias,
    float* __restrict__ out, long r0, int n0, int l15, int lhi)
{
#pragma unroll
    for (int cf = 0; cf < 4; ++cf) {
        const int c0 = n0 + cf * 16 + lhi * 4;
        float4 b4 = *(const float4*)(bias + c0);
#pragma unroll
        for (int rf = 0; rf < 8; ++rf) {
            float4 o = { acc[rf][cf][0] + b4.x, acc[rf][cf][1] + b4.y,
                         acc[rf][cf][2] + b4.z, acc[rf][cf][3] + b4.w };
            *(float4*)(out + (r0 + rf * 16 + l15) * 512 + c0) = o;
        }
    }
}

// ---------- kernel 1: cast all weights to bf16 into ws ----------
__global__ __launch_bounds__(256) void cast_kernel(
    const float* __restrict__ W1, const float* __restrict__ W2,
    const float* __restrict__ muW, const float* __restrict__ lvW,
    const float* __restrict__ Wqkv, const float* __restrict__ Wo,
    const float* __restrict__ Wc, const float* __restrict__ Wd1,
    const float* __restrict__ Wd2, const float* __restrict__ Wd3,
    bf16_t* __restrict__ dst)
{
    int i = blockIdx.x * 256 + threadIdx.x;   // grid exactly covers 1376256
    const float* src; int off;
    if      (i <  262144) { src = W1;   off = 0; }
    else if (i <  524288) { src = W2;   off = 262144; }
    else if (i <  655360) { src = muW;  off = 524288; }
    else if (i <  786432) { src = lvW;  off = 655360; }
    else if (i <  798720) { src = Wqkv; off = 786432; }
    else if (i <  802816) { src = Wo;   off = 798720; }
    else if (i <  819200) { src = Wc;   off = 802816; }
    else if (i <  851968) { src = Wd1;  off = 819200; }
    else if (i < 1114112) { src = Wd2;  off = 851968; }
    else                  { src = Wd3;  off = 1114112; }
    dst[i] = (bf16_t)src[i - off];
}

// ---------- kernel 2: encoder + heads + reparameterize (128-row blocks) ----------
__global__ __launch_bounds__(512, 2) void enc_kernel(
    const float* __restrict__ x, const float* __restrict__ eps,
    const bf16_t* __restrict__ W1b, const float* __restrict__ b1,
    const bf16_t* __restrict__ W2b, const float* __restrict__ b2,
    const bf16_t* __restrict__ Hb,  const float* __restrict__ mub,
    const float* __restrict__ lvb,  bf16_t* __restrict__ zout)
{
    __shared__ bf16_t act[128 * 512];   // 128 KB, in-place across layers
    const int t = threadIdx.x;
    const int wave = t >> 6, lane = t & 63, l15 = lane & 15, lhi = lane >> 4;
    const int n0 = wave * 64;
    const size_t r0 = (size_t)blockIdx.x * 128;

    // stage x tile (fp32 -> bf16, swizzled)
    for (int it = 0; it < 32; ++it) {
        int flat = it * 512 + t;
        int row = flat >> 7, c4 = flat & 127;
        float4 v = ((const float4*)(x + (r0 + row) * 512))[c4];
        bf16x4 h = { (bf16_t)v.x, (bf16_t)v.y, (bf16_t)v.z, (bf16_t)v.w };
        int byte = (row << 10) + (c4 << 3);
        byte ^= ((row & 7) << 4);
        *(bf16x4*)((char*)act + byte) = h;
    }
    __syncthreads();

    f32x4 acc[8][4];
    {   // layer 1
        zero_acc(acc);
        gemm_w128<512>(acc, act, 1024, W1b, n0, l15, lhi);
        __syncthreads();
        epi_act<true>(acc, b1, act, n0, l15, lhi);
        __syncthreads();
    }
    {   // layer 2
        zero_acc(acc);
        gemm_w128<512>(acc, act, 1024, W2b, n0, l15, lhi);
        __syncthreads();
        epi_act<true>(acc, b2, act, n0, l15, lhi);
        __syncthreads();
    }
    {   // heads: cols 0-255 mu, 256-511 lv
        zero_acc(acc);
        gemm_w128<512>(acc, act, 1024, Hb, n0, l15, lhi);
        __syncthreads();
        epi_act<false>(acc, (n0 < 256) ? mub : (lvb - 256), act, n0, l15, lhi);
        __syncthreads();
    }

    // z = mu + eps * T^1.5 * exp(0.5*lv); mu cols 0-255, lv cols 256-511
    const int cc = (t & 63) * 4;
    const int ag = cc >> 6;
    const float tp = (ag == 0) ? 1.8371173070873836f
                   : (ag == 1) ? 0.35355339059327373f
                   : (ag == 2) ? 1.0f
                               : 0.7155417527999327f;
    const int rb = t >> 6;
    for (int it = 0; it < 16; ++it) {
        int row = it * 8 + rb;
        bf16x4 mu4 = lds_read8B(act, row, cc, 1024);
        bf16x4 lv4 = lds_read8B(act, row, cc + 256, 1024);
        float4 ep4 = *(const float4*)(eps + (r0 + row) * 256 + cc);
        bf16x4 zo;
        zo[0] = (bf16_t)fmaf(ep4.x * tp, expf(0.5f * (float)lv4[0]), (float)mu4[0]);
        zo[1] = (bf16_t)fmaf(ep4.y * tp, expf(0.5f * (float)lv4[1]), (float)mu4[1]);
        zo[2] = (bf16_t)fmaf(ep4.z * tp, expf(0.5f * (float)lv4[2]), (float)mu4[2]);
        zo[3] = (bf16_t)fmaf(ep4.w * tp, expf(0.5f * (float)lv4[3]), (float)mu4[3]);
        *(bf16x4*)(zout + (r0 + row) * 256 + cc) = zo;
    }
}

// ---------- kernel 3: attention over 4 agents + consensus (unchanged) ----------
__global__ __launch_bounds__(512) void attn_kernel(
    const bf16_t* __restrict__ z,
    const bf16_t* __restrict__ Wqkvb, const float* __restrict__ bqkv,
    const bf16_t* __restrict__ Wob,   const float* __restrict__ bo,
    const bf16_t* __restrict__ Wcb,   const float* __restrict__ bc,
    bf16_t* __restrict__ zcb)
{
    __shared__ bf16_t zt[256 * 64];    // z tile, later ctx tile   (rowB 128)
    __shared__ bf16_t qt[256 * 192];   // qkv tile, later z_att    (rowB 384/128)
    const int t = threadIdx.x;
    const size_t s0 = (size_t)blockIdx.x * 64;

    for (int it = 0; it < 4; ++it) {
        int ch = it * 512 + t;
        int r = ch >> 3, cc = ch & 7;
        bf16x8 v = *(const bf16x8*)(z + s0 * 256 + r * 64 + cc * 8);
        lds_write16B(zt, r, cc * 16, 128, v);
    }
    __syncthreads();
    const int wave = t >> 6, lane = t & 63, l15 = lane & 15, lhi = lane >> 4;
    const int rbase = wave * 32;

    for (int cc = 0; cc < 4; ++cc) {
        f32x4 acc[2][3] = {};
#pragma unroll
        for (int ks = 0; ks < 2; ++ks) {
            int k = ks * 32 + lhi * 8;
            bf16x8 a0 = lds_read8(zt, rbase + l15, k, 128);
            bf16x8 a1 = lds_read8(zt, rbase + 16 + l15, k, 128);
#pragma unroll
            for (int cf = 0; cf < 3; ++cf) {
                bf16x8 b = *(const bf16x8*)(Wqkvb + (cc * 48 + cf * 16 + l15) * 64 + k);
                acc[0][cf] = MFMA16(a0, b, acc[0][cf]);
                acc[1][cf] = MFMA16(a1, b, acc[1][cf]);
            }
        }
#pragma unroll
        for (int cf = 0; cf < 3; ++cf) {
            int col = cc * 48 + cf * 16 + l15;
            float bs = bqkv[col];
#pragma unroll
            for (int rf = 0; rf < 2; ++rf)
#pragma unroll
                for (int r = 0; r < 4; ++r)
                    lds_write1(qt, rbase + rf * 16 + lhi * 4 + r, col, 384, acc[rf][cf][r] + bs);
        }
    }
    __syncthreads();

    if (t < 256) {
        const int sl = t >> 2, head = t & 3;
        bf16x8 qv[4][2], kv[4][2], vv[4][2];
#pragma unroll
        for (int a2 = 0; a2 < 4; ++a2) {
            int r = sl * 4 + a2;
#pragma unroll
            for (int i = 0; i < 2; ++i) {
                qv[a2][i] = lds_read16B(qt, r, head * 32 + 16 * i, 384);
                kv[a2][i] = lds_read16B(qt, r, 128 + head * 32 + 16 * i, 384);
                vv[a2][i] = lds_read16B(qt, r, 256 + head * 32 + 16 * i, 384);
            }
        }
        float sc[4][4];
#pragma unroll
        for (int qa = 0; qa < 4; ++qa)
#pragma unroll
            for (int ka = 0; ka < 4; ++ka) {
                float s = 0.f;
#pragma unroll
                for (int i = 0; i < 2; ++i)
#pragma unroll
                    for (int j = 0; j < 8; ++j)
                        s += (float)qv[qa][i][j] * (float)kv[ka][i][j];
                sc[qa][ka] = s * 0.25f;
            }
#pragma unroll
        for (int qa = 0; qa < 4; ++qa) {
            float m = fmaxf(fmaxf(sc[qa][0], sc[qa][1]), fmaxf(sc[qa][2], sc[qa][3]));
            float e[4], sum = 0.f;
#pragma unroll
            for (int ka = 0; ka < 4; ++ka) { e[ka] = expf(sc[qa][ka] - m); sum += e[ka]; }
            float inv = 1.f / sum;
#pragma unroll
            for (int i = 0; i < 2; ++i) {
                bf16x8 cv;
#pragma unroll
                for (int j = 0; j < 8; ++j) {
                    float cval = 0.f;
#pragma unroll
                    for (int ka = 0; ka < 4; ++ka) cval += e[ka] * inv * (float)vv[ka][i][j];
                    cv[j] = (bf16_t)cval;
                }
                lds_write16B(zt, sl * 4 + qa, head * 32 + 16 * i, 128, cv);
            }
        }
    }
    __syncthreads();

    {   // z_att = ctx @ Wo^T + bo
        f32x4 acc[2][4] = {};
#pragma unroll
        for (int ks = 0; ks < 2; ++ks) {
            int k = ks * 32 + lhi * 8;
            bf16x8 a0 = lds_read8(zt, rbase + l15, k, 128);
            bf16x8 a1 = lds_read8(zt, rbase + 16 + l15, k, 128);
#pragma unroll
            for (int cf = 0; cf < 4; ++cf) {
                bf16x8 b = *(const bf16x8*)(Wob + (cf * 16 + l15) * 64 + k);
                acc[0][cf] = MFMA16(a0, b, acc[0][cf]);
                acc[1][cf] = MFMA16(a1, b, acc[1][cf]);
            }
        }
        __syncthreads();
#pragma unroll
        for (int cf = 0; cf < 4; ++cf) {
            int col = cf * 16 + l15;
            float bs = bo[col];
#pragma unroll
            for (int rf = 0; rf < 2; ++rf)
#pragma unroll
                for (int r = 0; r < 4; ++r)
                    lds_write1(qt, rbase + rf * 16 + lhi * 4 + r, col, 128, acc[rf][cf][r] + bs);
        }
    }
    __syncthreads();

    {   // z_consensus = z_att.reshape(64,256) @ Wc^T + bc
        f32x4 acc2[2] = {};
        const int rfw = wave >> 1, cbase = (wave & 1) * 2;
        const int srow = rfw * 16 + l15;
#pragma unroll
        for (int ks = 0; ks < 8; ++ks) {
            int k = ks * 32 + lhi * 8;
            int byte = (srow << 9) + (k << 1);
            byte ^= ((((srow << 2) + (k >> 6)) & 7) << 4);
            bf16x8 a = *(const bf16x8*)((const char*)qt + byte);
#pragma unroll
            for (int i = 0; i < 2; ++i) {
                bf16x8 b = *(const bf16x8*)(Wcb + ((cbase + i) * 16 + l15) * 256 + k);
                acc2[i] = MFMA16(a, b, acc2[i]);
            }
        }
#pragma unroll
        for (int i = 0; i < 2; ++i) {
            int col = (cbase + i) * 16 + l15;
            float bs = bc[col];
#pragma unroll
            for (int r = 0; r < 4; ++r) {
                int s = (int)(s0) + rfw * 16 + lhi * 4 + r;
                zcb[(size_t)s * 64 + col] = (bf16_t)(acc2[i][r] + bs);
            }
        }
    }
}

// ---------- kernel 4: fused 3-layer decoder (128-row blocks) ----------
__global__ __launch_bounds__(512, 2) void dec_kernel(
    const bf16_t* __restrict__ z, const bf16_t* __restrict__ zc,
    const bf16_t* __restrict__ Wd1b, const float* __restrict__ bd1,
    const bf16_t* __restrict__ Wd2b, const float* __restrict__ bd2,
    const bf16_t* __restrict__ Wd3b, const float* __restrict__ bd3,
    float* __restrict__ out)
{
    __shared__ bf16_t zz[128 * 64];     // 16 KB latent tile (rowB 128)
    __shared__ bf16_t act[128 * 512];   // 128 KB, in-place across layers
    const int t = threadIdx.x;
    const int wave = t >> 6, lane = t & 63, l15 = lane & 15, lhi = lane >> 4;
    const int n0 = wave * 64;
    const long r0 = (long)blockIdx.x * 128;

    // gather latent rows: row = s*5 + j; j==0 -> consensus, else agent j-1
    for (int it = 0; it < 2; ++it) {
        int flat = it * 512 + t;
        int row = flat >> 3, ch = flat & 7;
        long rg = r0 + row;
        int s5 = (int)(rg / 5), j = (int)(rg - (long)s5 * 5);
        const bf16_t* src = (j == 0) ? (zc + (size_t)s5 * 64)
                                     : (z + (size_t)s5 * 256 + (j - 1) * 64);
        bf16x8 v = *(const bf16x8*)(src + ch * 8);
        int byte = (row << 7) + (ch << 4);
        byte ^= ((row & 7) << 4);
        *(bf16x8*)((char*)zz + byte) = v;
    }
    __syncthreads();

    f32x4 acc[8][4];
    {   // layer 1: K=64 from zz -> act (act not yet read; one barrier after)
        zero_acc(acc);
        gemm_w128<64>(acc, zz, 128, Wd1b, n0, l15, lhi);
        epi_act<true>(acc, bd1, act, n0, l15, lhi);
        __syncthreads();
    }
    {   // layer 2 (in-place)
        zero_acc(acc);
        gemm_w128<512>(acc, act, 1024, Wd2b, n0, l15, lhi);
        __syncthreads();
        epi_act<true>(acc, bd2, act, n0, l15, lhi);
        __syncthreads();
    }
    {   // layer 3 -> global fp32 (float4 coalesced)
        zero_acc(acc);
        gemm_w128<512>(acc, act, 1024, Wd3b, n0, l15, lhi);
        epi_out(acc, bd3, out, r0, n0, l15, lhi);
    }
}

// ---------- launcher ----------
extern "C" void kernel_launch(void* const* d_in, const int* in_sizes, int n_in,
                              void* d_out, int out_size, void* d_ws, size_t ws_size,
                              hipStream_t stream) {
    const float* x    = (const float*)d_in[0];
    const float* eps  = (const float*)d_in[1];
    const float* W1   = (const float*)d_in[2];
    const float* b1   = (const float*)d_in[3];
    const float* W2   = (const float*)d_in[4];
    const float* b2   = (const float*)d_in[5];
    const float* muW  = (const float*)d_in[6];
    const float* mub  = (const float*)d_in[7];
    const float* lvW  = (const float*)d_in[8];
    const float* lvb  = (const float*)d_in[9];
    const float* Wqkv = (const float*)d_in[10];
    const float* bqkv = (const float*)d_in[11];
    const float* Wo   = (const float*)d_in[12];
    const float* bo   = (const float*)d_in[13];
    const float* Wc   = (const float*)d_in[14];
    const float* bc   = (const float*)d_in[15];
    const float* Wd1  = (const float*)d_in[16];
    const float* bd1  = (const float*)d_in[17];
    const float* Wd2  = (const float*)d_in[18];
    const float* bd2  = (const float*)d_in[19];
    const float* Wd3  = (const float*)d_in[20];
    const float* bd3  = (const float*)d_in[21];
    float* out = (float*)d_out;

    bf16_t* wsb  = (bf16_t*)d_ws;
    bf16_t* W1b  = wsb + 0;
    bf16_t* W2b  = wsb + 262144;
    bf16_t* Hb   = wsb + 524288;    // [muW(256x512) ; lvW(256x512)]
    bf16_t* Wqkvb= wsb + 786432;
    bf16_t* Wob  = wsb + 798720;
    bf16_t* Wcb  = wsb + 802816;
    bf16_t* Wd1b = wsb + 819200;
    bf16_t* Wd2b = wsb + 851968;
    bf16_t* Wd3b = wsb + 1114112;
    bf16_t* zbuf = wsb + 1376256;   // (B,256) bf16
    bf16_t* zcb  = wsb + 9764864;   // (B,64)  bf16

    cast_kernel<<<dim3(5376), dim3(256), 0, stream>>>(
        W1, W2, muW, lvW, Wqkv, Wo, Wc, Wd1, Wd2, Wd3, wsb);
    enc_kernel<<<dim3(256), dim3(512), 0, stream>>>(
        x, eps, W1b, b1, W2b, b2, Hb, mub, lvb, zbuf);
    attn_kernel<<<dim3(512), dim3(512), 0, stream>>>(
        zbuf, Wqkvb, bqkv, Wob, bo, Wcb, bc, zcb);
    dec_kernel<<<dim3(1280), dim3(512), 0, stream>>>(
        zbuf, zcb, Wd1b, bd1, Wd2b, bd2, Wd3b, bd3, out);
}

// Round 9
// 435.440 us; speedup vs baseline: 1.4546x; 1.3975x over previous
//
#include <hip/hip_runtime.h>

typedef __bf16 bf16_t;
typedef __bf16 bf16x8 __attribute__((ext_vector_type(8)));
typedef __bf16 bf16x4 __attribute__((ext_vector_type(4)));
typedef float  f32x4  __attribute__((ext_vector_type(4)));

#define MFMA16(a,b,c) __builtin_amdgcn_mfma_f32_16x16x32_bf16((a),(b),(c),0,0,0)
#define GLOBAL_AS __attribute__((address_space(1)))
#define LDS_AS    __attribute__((address_space(3)))

// ---------- LDS helpers with XOR swizzle (byte ^= (row&7)<<4) ----------
__device__ __forceinline__ bf16x8 lds_read8(const bf16_t* base, int row, int k, int rowB) {
    int byte = row * rowB + (k << 1);
    byte ^= ((row & 7) << 4);
    return *(const bf16x8*)((const char*)base + byte);
}
__device__ __forceinline__ void lds_write8B(bf16_t* base, int row, int col, int rowB, bf16x4 v) {
    int byte = row * rowB + (col << 1);
    byte ^= ((row & 7) << 4);
    *(bf16x4*)((char*)base + byte) = v;
}
__device__ __forceinline__ bf16x4 lds_read8B(const bf16_t* base, int row, int col, int rowB) {
    int byte = row * rowB + (col << 1);
    byte ^= ((row & 7) << 4);
    return *(const bf16x4*)((const char*)base + byte);
}
__device__ __forceinline__ void lds_write1(bf16_t* base, int row, int col, int rowB, float v) {
    int byte = row * rowB + (col << 1);
    byte ^= ((row & 7) << 4);
    *(bf16_t*)((char*)base + byte) = (bf16_t)v;
}
__device__ __forceinline__ void lds_write16B(bf16_t* base, int row, int colbyte, int rowB, bf16x8 v) {
    int byte = row * rowB + colbyte;
    byte ^= ((row & 7) << 4);
    *(bf16x8*)((char*)base + byte) = v;
}
__device__ __forceinline__ bf16x8 lds_read16B(const bf16_t* base, int row, int colbyte, int rowB) {
    int byte = row * rowB + colbyte;
    byte ^= ((row & 7) << 4);
    return *(const bf16x8*)((const char*)base + byte);
}

// ---------- global_load_lds staging of retiled W ----------
// Retiled layout: tile = one K-step (BK=32) = 32KB: byte o in tile:
//   kg = o/8192 (k-subgroup, 8 bf16), col = (o%8192)/16, j = bytes within 16B.
// Element (col n, k = tile*32 + kg*8 + j).
__device__ __forceinline__ void gload_lds16(const void* g, void* l) {
    __builtin_amdgcn_global_load_lds((const GLOBAL_AS void*)g, (LDS_AS void*)l, 16, 0, 0);
}
__device__ __forceinline__ void stageW(const bf16_t* __restrict__ Wt, int tile,
                                       char* wbuf, int bufIdx, int wave, int lane) {
    const char* s = (const char*)Wt + (size_t)tile * 32768 + wave * 4096 + lane * 16;
    char* d = wbuf + bufIdx * 32768 + wave * 4096;
#pragma unroll
    for (int c = 0; c < 4; ++c)
        gload_lds16(s + c * 1024, d + c * 1024);
}

// ---------- pipelined layer: 3 W-buffers, counted vmcnt, raw barriers ----------
// Per-wave tile 64 rows x 64 cols, acc[4][4]. SWAPPED MFMA16(b,a,acc):
// C[row = rf*16+l15][col = n0+cf*16+lhi*4+r]
template<int NS, bool CONT, int TB>
__device__ __forceinline__ void layer_gl(f32x4 (&acc)[4][4],
    const bf16_t* act, char* wbuf,
    const bf16_t* __restrict__ Wt, const bf16_t* __restrict__ Wn,
    int wave, int lane, int n0, int l15, int lhi)
{
#pragma unroll
    for (int s = 0; s < NS; ++s) {
        if (s == NS - 1 && !CONT) {
            asm volatile("s_waitcnt vmcnt(0)" ::: "memory");
        } else {
            asm volatile("s_waitcnt vmcnt(4)" ::: "memory");   // tile s done; s+1,(s+2) in flight
        }
        __builtin_amdgcn_s_barrier();
        if (s + 2 < NS)  stageW(Wt, s + 2,      wbuf, (TB + s + 2) % 3, wave, lane);
        else if (CONT)   stageW(Wn, s + 2 - NS, wbuf, (TB + s + 2) % 3, wave, lane);
        const char* bb = wbuf + ((TB + s) % 3) * 32768 + lhi * 8192;
        bf16x8 a[4], b[4];
#pragma unroll
        for (int cf = 0; cf < 4; ++cf)
            b[cf] = *(const bf16x8*)(bb + (n0 + cf * 16 + l15) * 16);
#pragma unroll
        for (int rf = 0; rf < 4; ++rf)
            a[rf] = lds_read8(act, rf * 16 + l15, s * 32 + lhi * 8, 1024);
#pragma unroll
        for (int rf = 0; rf < 4; ++rf)
#pragma unroll
            for (int cf = 0; cf < 4; ++cf)
                acc[rf][cf] = MFMA16(b[cf], a[rf], acc[rf][cf]);
    }
}

__device__ __forceinline__ void zero4(f32x4 (&acc)[4][4]) {
#pragma unroll
    for (int rf = 0; rf < 4; ++rf)
#pragma unroll
        for (int cf = 0; cf < 4; ++cf)
            acc[rf][cf] = f32x4{0.f, 0.f, 0.f, 0.f};
}

template<bool RELU>
__device__ __forceinline__ void epi_lds(const f32x4 (&acc)[4][4], const float* __restrict__ bias,
    bf16_t* dst, int rowB, int n0, int l15, int lhi)
{
#pragma unroll
    for (int cf = 0; cf < 4; ++cf) {
        const int c0 = n0 + cf * 16 + lhi * 4;
        float4 b4 = *(const float4*)(bias + c0);
#pragma unroll
        for (int rf = 0; rf < 4; ++rf) {
            float v0 = acc[rf][cf][0] + b4.x;
            float v1 = acc[rf][cf][1] + b4.y;
            float v2 = acc[rf][cf][2] + b4.z;
            float v3 = acc[rf][cf][3] + b4.w;
            if (RELU) {
                v0 = fmaxf(v0, 0.f); v1 = fmaxf(v1, 0.f);
                v2 = fmaxf(v2, 0.f); v3 = fmaxf(v3, 0.f);
            }
            bf16x4 p = { (bf16_t)v0, (bf16_t)v1, (bf16_t)v2, (bf16_t)v3 };
            lds_write8B(dst, rf * 16 + l15, c0, rowB, p);
        }
    }
}

__device__ __forceinline__ void epi_global(const f32x4 (&acc)[4][4], const float* __restrict__ bias,
    float* __restrict__ out, long row0, int n0, int l15, int lhi)
{
#pragma unroll
    for (int cf = 0; cf < 4; ++cf) {
        const int c0 = n0 + cf * 16 + lhi * 4;
        float4 b4 = *(const float4*)(bias + c0);
#pragma unroll
        for (int rf = 0; rf < 4; ++rf) {
            float4 o = { acc[rf][cf][0] + b4.x, acc[rf][cf][1] + b4.y,
                         acc[rf][cf][2] + b4.z, acc[rf][cf][3] + b4.w };
            *(float4*)(out + (row0 + rf * 16 + l15) * 512 + c0) = o;
        }
    }
}

// ---------- kernel 1: cast + retile weights to bf16 into ws ----------
// GEMM weights -> tiled layout [tile][kg][col][8]; attn weights row-major.
__device__ __forceinline__ void decode_tile(int m, int& n, int& k) {
    int s = m >> 14, r = m & 16383;
    int kg = r >> 12, q = r & 4095;
    n = q >> 3;
    k = (s << 5) + (kg << 3) + (q & 7);
}
__global__ __launch_bounds__(256) void cast_kernel(
    const float* __restrict__ W1, const float* __restrict__ W2,
    const float* __restrict__ muW, const float* __restrict__ lvW,
    const float* __restrict__ Wqkv, const float* __restrict__ Wo,
    const float* __restrict__ Wc, const float* __restrict__ Wd1,
    const float* __restrict__ Wd2, const float* __restrict__ Wd3,
    bf16_t* __restrict__ dst)
{
    int i = blockIdx.x * 256 + threadIdx.x;   // grid exactly covers 1376256
    float val;
    int n, k;
    if (i < 262144) {
        decode_tile(i, n, k);                     val = W1[n * 512 + k];
    } else if (i < 524288) {
        decode_tile(i - 262144, n, k);            val = W2[n * 512 + k];
    } else if (i < 786432) {
        decode_tile(i - 524288, n, k);
        val = (n < 256) ? muW[n * 512 + k] : lvW[(n - 256) * 512 + k];
    } else if (i < 798720) { val = Wqkv[i - 786432]; }
    else if (i < 802816)   { val = Wo[i - 798720]; }
    else if (i < 819200)   { val = Wc[i - 802816]; }
    else if (i < 851968) {
        decode_tile(i - 819200, n, k);            val = Wd1[n * 64 + k];
    } else if (i < 1114112) {
        decode_tile(i - 851968, n, k);            val = Wd2[n * 512 + k];
    } else {
        decode_tile(i - 1114112, n, k);           val = Wd3[n * 512 + k];
    }
    dst[i] = (bf16_t)val;
}

// ---------- kernel 2: encoder + heads + reparameterize ----------
__global__ __launch_bounds__(512, 2) void enc_kernel(
    const float* __restrict__ x, const float* __restrict__ eps,
    const bf16_t* __restrict__ W1t, const float* __restrict__ b1,
    const bf16_t* __restrict__ W2t, const float* __restrict__ b2,
    const bf16_t* __restrict__ Ht,  const float* __restrict__ mub,
    const float* __restrict__ lvb,  bf16_t* __restrict__ zout)
{
    __shared__ bf16_t act[64 * 512];            // 64 KB
    __shared__ alignas(16) char wbuf[3 * 32768];// 96 KB
    const int t = threadIdx.x;
    const int wave = t >> 6, lane = t & 63, l15 = lane & 15, lhi = lane >> 4;
    const int n0 = wave * 64;
    const size_t r0 = (size_t)blockIdx.x * 64;

    stageW(W1t, 0, wbuf, 0, wave, lane);
    stageW(W1t, 1, wbuf, 1, wave, lane);

    // stage x tile (fp32 -> bf16, swizzled)
    for (int it = 0; it < 16; ++it) {
        int flat = it * 512 + t;
        int row = flat >> 7, c4 = flat & 127;
        float4 v = ((const float4*)(x + (r0 + row) * 512))[c4];
        bf16x4 h = { (bf16_t)v.x, (bf16_t)v.y, (bf16_t)v.z, (bf16_t)v.w };
        int byte = (row << 10) + (c4 << 3);
        byte ^= ((row & 7) << 4);
        *(bf16x4*)((char*)act + byte) = h;
    }
    asm volatile("s_waitcnt lgkmcnt(0)" ::: "memory");

    f32x4 acc[4][4];
    zero4(acc);
    layer_gl<16, true, 0>(acc, act, wbuf, W1t, W2t, wave, lane, n0, l15, lhi);
    __builtin_amdgcn_s_barrier();
    epi_lds<true>(acc, b1, act, 1024, n0, l15, lhi);
    asm volatile("s_waitcnt lgkmcnt(0)" ::: "memory");
    __builtin_amdgcn_s_barrier();

    zero4(acc);
    layer_gl<16, true, 1>(acc, act, wbuf, W2t, Ht, wave, lane, n0, l15, lhi);
    __builtin_amdgcn_s_barrier();
    epi_lds<true>(acc, b2, act, 1024, n0, l15, lhi);
    asm volatile("s_waitcnt lgkmcnt(0)" ::: "memory");
    __builtin_amdgcn_s_barrier();

    zero4(acc);
    layer_gl<16, false, 2>(acc, act, wbuf, Ht, (const bf16_t*)nullptr, wave, lane, n0, l15, lhi);
    __builtin_amdgcn_s_barrier();
    epi_lds<false>(acc, (n0 < 256) ? mub : (lvb - 256), act, 1024, n0, l15, lhi);
    asm volatile("s_waitcnt lgkmcnt(0)" ::: "memory");
    __builtin_amdgcn_s_barrier();

    // z = mu + eps * T^1.5 * exp(0.5*lv); mu cols 0-255, lv cols 256-511
    const int cc = (t & 63) * 4;
    const int ag = cc >> 6;
    const float tp = (ag == 0) ? 1.8371173070873836f
                   : (ag == 1) ? 0.35355339059327373f
                   : (ag == 2) ? 1.0f
                               : 0.7155417527999327f;
    const int rb = t >> 6;
    for (int it = 0; it < 8; ++it) {
        int row = it * 8 + rb;
        bf16x4 mu4 = lds_read8B(act, row, cc, 1024);
        bf16x4 lv4 = lds_read8B(act, row, cc + 256, 1024);
        float4 ep4 = *(const float4*)(eps + (r0 + row) * 256 + cc);
        bf16x4 zo;
        zo[0] = (bf16_t)fmaf(ep4.x * tp, expf(0.5f * (float)lv4[0]), (float)mu4[0]);
        zo[1] = (bf16_t)fmaf(ep4.y * tp, expf(0.5f * (float)lv4[1]), (float)mu4[1]);
        zo[2] = (bf16_t)fmaf(ep4.z * tp, expf(0.5f * (float)lv4[2]), (float)mu4[2]);
        zo[3] = (bf16_t)fmaf(ep4.w * tp, expf(0.5f * (float)lv4[3]), (float)mu4[3]);
        *(bf16x4*)(zout + (r0 + row) * 256 + cc) = zo;
    }
}

// ---------- kernel 3: attention over 4 agents + consensus (unchanged) ----------
__global__ __launch_bounds__(512) void attn_kernel(
    const bf16_t* __restrict__ z,
    const bf16_t* __restrict__ Wqkvb, const float* __restrict__ bqkv,
    const bf16_t* __restrict__ Wob,   const float* __restrict__ bo,
    const bf16_t* __restrict__ Wcb,   const float* __restrict__ bc,
    bf16_t* __restrict__ zcb)
{
    __shared__ bf16_t zt[256 * 64];    // z tile, later ctx tile   (rowB 128)
    __shared__ bf16_t qt[256 * 192];   // qkv tile, later z_att    (rowB 384/128)
    const int t = threadIdx.x;
    const size_t s0 = (size_t)blockIdx.x * 64;

    for (int it = 0; it < 4; ++it) {
        int ch = it * 512 + t;
        int r = ch >> 3, cc = ch & 7;
        bf16x8 v = *(const bf16x8*)(z + s0 * 256 + r * 64 + cc * 8);
        lds_write16B(zt, r, cc * 16, 128, v);
    }
    __syncthreads();
    const int wave = t >> 6, lane = t & 63, l15 = lane & 15, lhi = lane >> 4;
    const int rbase = wave * 32;

    for (int cc = 0; cc < 4; ++cc) {
        f32x4 acc[2][3] = {};
#pragma unroll
        for (int ks = 0; ks < 2; ++ks) {
            int k = ks * 32 + lhi * 8;
            bf16x8 a0 = lds_read8(zt, rbase + l15, k, 128);
            bf16x8 a1 = lds_read8(zt, rbase + 16 + l15, k, 128);
#pragma unroll
            for (int cf = 0; cf < 3; ++cf) {
                bf16x8 b = *(const bf16x8*)(Wqkvb + (cc * 48 + cf * 16 + l15) * 64 + k);
                acc[0][cf] = MFMA16(a0, b, acc[0][cf]);
                acc[1][cf] = MFMA16(a1, b, acc[1][cf]);
            }
        }
#pragma unroll
        for (int cf = 0; cf < 3; ++cf) {
            int col = cc * 48 + cf * 16 + l15;
            float bs = bqkv[col];
#pragma unroll
            for (int rf = 0; rf < 2; ++rf)
#pragma unroll
                for (int r = 0; r < 4; ++r)
                    lds_write1(qt, rbase + rf * 16 + lhi * 4 + r, col, 384, acc[rf][cf][r] + bs);
        }
    }
    __syncthreads();

    if (t < 256) {
        const int sl = t >> 2, head = t & 3;
        bf16x8 qv[4][2], kv[4][2], vv[4][2];
#pragma unroll
        for (int a2 = 0; a2 < 4; ++a2) {
            int r = sl * 4 + a2;
#pragma unroll
            for (int i = 0; i < 2; ++i) {
                qv[a2][i] = lds_read16B(qt, r, head * 32 + 16 * i, 384);
                kv[a2][i] = lds_read16B(qt, r, 128 + head * 32 + 16 * i, 384);
                vv[a2][i] = lds_read16B(qt, r, 256 + head * 32 + 16 * i, 384);
            }
        }
        float sc[4][4];
#pragma unroll
        for (int qa = 0; qa < 4; ++qa)
#pragma unroll
            for (int ka = 0; ka < 4; ++ka) {
                float s = 0.f;
#pragma unroll
                for (int i = 0; i < 2; ++i)
#pragma unroll
                    for (int j = 0; j < 8; ++j)
                        s += (float)qv[qa][i][j] * (float)kv[ka][i][j];
                sc[qa][ka] = s * 0.25f;
            }
#pragma unroll
        for (int qa = 0; qa < 4; ++qa) {
            float m = fmaxf(fmaxf(sc[qa][0], sc[qa][1]), fmaxf(sc[qa][2], sc[qa][3]));
            float e[4], sum = 0.f;
#pragma unroll
            for (int ka = 0; ka < 4; ++ka) { e[ka] = expf(sc[qa][ka] - m); sum += e[ka]; }
            float inv = 1.f / sum;
#pragma unroll
            for (int i = 0; i < 2; ++i) {
                bf16x8 cv;
#pragma unroll
                for (int j = 0; j < 8; ++j) {
                    float cval = 0.f;
#pragma unroll
                    for (int ka = 0; ka < 4; ++ka) cval += e[ka] * inv * (float)vv[ka][i][j];
                    cv[j] = (bf16_t)cval;
                }
                lds_write16B(zt, sl * 4 + qa, head * 32 + 16 * i, 128, cv);
            }
        }
    }
    __syncthreads();

    {   // z_att = ctx @ Wo^T + bo
        f32x4 acc[2][4] = {};
#pragma unroll
        for (int ks = 0; ks < 2; ++ks) {
            int k = ks * 32 + lhi * 8;
            bf16x8 a0 = lds_read8(zt, rbase + l15, k, 128);
            bf16x8 a1 = lds_read8(zt, rbase + 16 + l15, k, 128);
#pragma unroll
            for (int cf = 0; cf < 4; ++cf) {
                bf16x8 b = *(const bf16x8*)(Wob + (cf * 16 + l15) * 64 + k);
                acc[0][cf] = MFMA16(a0, b, acc[0][cf]);
                acc[1][cf] = MFMA16(a1, b, acc[1][cf]);
            }
        }
        __syncthreads();
#pragma unroll
        for (int cf = 0; cf < 4; ++cf) {
            int col = cf * 16 + l15;
            float bs = bo[col];
#pragma unroll
            for (int rf = 0; rf < 2; ++rf)
#pragma unroll
                for (int r = 0; r < 4; ++r)
                    lds_write1(qt, rbase + rf * 16 + lhi * 4 + r, col, 128, acc[rf][cf][r] + bs);
        }
    }
    __syncthreads();

    {   // z_consensus = z_att.reshape(64,256) @ Wc^T + bc
        f32x4 acc2[2] = {};
        const int rfw = wave >> 1, cbase = (wave & 1) * 2;
        const int srow = rfw * 16 + l15;
#pragma unroll
        for (int ks = 0; ks < 8; ++ks) {
            int k = ks * 32 + lhi * 8;
            int byte = (srow << 9) + (k << 1);
            byte ^= ((((srow << 2) + (k >> 6)) & 7) << 4);
            bf16x8 a = *(const bf16x8*)((const char*)qt + byte);
#pragma unroll
            for (int i = 0; i < 2; ++i) {
                bf16x8 b = *(const bf16x8*)(Wcb + ((cbase + i) * 16 + l15) * 256 + k);
                acc2[i] = MFMA16(a, b, acc2[i]);
            }
        }
#pragma unroll
        for (int i = 0; i < 2; ++i) {
            int col = (cbase + i) * 16 + l15;
            float bs = bc[col];
#pragma unroll
            for (int r = 0; r < 4; ++r) {
                int s = (int)(s0) + rfw * 16 + lhi * 4 + r;
                zcb[(size_t)s * 64 + col] = (bf16_t)(acc2[i][r] + bs);
            }
        }
    }
}

// ---------- kernel 4: fused 3-layer decoder (pipelined global_load_lds) ----------
__global__ __launch_bounds__(512, 2) void dec_kernel(
    const bf16_t* __restrict__ z, const bf16_t* __restrict__ zc,
    const bf16_t* __restrict__ Wd1t, const float* __restrict__ bd1,
    const bf16_t* __restrict__ Wd2t, const float* __restrict__ bd2,
    const bf16_t* __restrict__ Wd3t, const float* __restrict__ bd3,
    float* __restrict__ out)
{
    __shared__ bf16_t act[64 * 512];            // 64 KB (latents staged in cols 0..63)
    __shared__ alignas(16) char wbuf[3 * 32768];// 96 KB
    const int t = threadIdx.x;
    const int wave = t >> 6, lane = t & 63, l15 = lane & 15, lhi = lane >> 4;
    const int n0 = wave * 64;
    const long r0 = (long)blockIdx.x * 64;

    stageW(Wd1t, 0, wbuf, 0, wave, lane);
    stageW(Wd1t, 1, wbuf, 1, wave, lane);

    {   // gather latent rows into act cols 0..63: row = s*5 + j
        int row = t >> 3, ch = t & 7;
        long rg = r0 + row;
        int s5 = (int)(rg / 5), j = (int)(rg - (long)s5 * 5);
        const bf16_t* src = (j == 0) ? (zc + (size_t)s5 * 64)
                                     : (z + (size_t)s5 * 256 + (j - 1) * 64);
        bf16x8 v = *(const bf16x8*)(src + ch * 8);
        int byte = (row << 10) + (ch << 4);
        byte ^= ((row & 7) << 4);
        *(bf16x8*)((char*)act + byte) = v;
    }
    asm volatile("s_waitcnt lgkmcnt(0)" ::: "memory");

    f32x4 acc[4][4];
    zero4(acc);
    layer_gl<2, true, 0>(acc, act, wbuf, Wd1t, Wd2t, wave, lane, n0, l15, lhi);
    __builtin_amdgcn_s_barrier();
    epi_lds<true>(acc, bd1, act, 1024, n0, l15, lhi);
    asm volatile("s_waitcnt lgkmcnt(0)" ::: "memory");
    __builtin_amdgcn_s_barrier();

    zero4(acc);
    layer_gl<16, true, 2>(acc, act, wbuf, Wd2t, Wd3t, wave, lane, n0, l15, lhi);
    __builtin_amdgcn_s_barrier();
    epi_lds<true>(acc, bd2, act, 1024, n0, l15, lhi);
    asm volatile("s_waitcnt lgkmcnt(0)" ::: "memory");
    __builtin_amdgcn_s_barrier();

    zero4(acc);
    layer_gl<16, false, 0>(acc, act, wbuf, Wd3t, (const bf16_t*)nullptr, wave, lane, n0, l15, lhi);
    epi_global(acc, bd3, out, r0, n0, l15, lhi);
}

// ---------- launcher ----------
extern "C" void kernel_launch(void* const* d_in, const int* in_sizes, int n_in,
                              void* d_out, int out_size, void* d_ws, size_t ws_size,
                              hipStream_t stream) {
    const float* x    = (const float*)d_in[0];
    const float* eps  = (const float*)d_in[1];
    const float* W1   = (const float*)d_in[2];
    const float* b1   = (const float*)d_in[3];
    const float* W2   = (const float*)d_in[4];
    const float* b2   = (const float*)d_in[5];
    const float* muW  = (const float*)d_in[6];
    const float* mub  = (const float*)d_in[7];
    const float* lvW  = (const float*)d_in[8];
    const float* lvb  = (const float*)d_in[9];
    const float* Wqkv = (const float*)d_in[10];
    const float* bqkv = (const float*)d_in[11];
    const float* Wo   = (const float*)d_in[12];
    const float* bo   = (const float*)d_in[13];
    const float* Wc   = (const float*)d_in[14];
    const float* bc   = (const float*)d_in[15];
    const float* Wd1  = (const float*)d_in[16];
    const float* bd1  = (const float*)d_in[17];
    const float* Wd2  = (const float*)d_in[18];
    const float* bd2  = (const float*)d_in[19];
    const float* Wd3  = (const float*)d_in[20];
    const float* bd3  = (const float*)d_in[21];
    float* out = (float*)d_out;

    bf16_t* wsb  = (bf16_t*)d_ws;
    bf16_t* W1t  = wsb + 0;
    bf16_t* W2t  = wsb + 262144;
    bf16_t* Ht   = wsb + 524288;    // [muW ; lvW] retiled
    bf16_t* Wqkvb= wsb + 786432;
    bf16_t* Wob  = wsb + 798720;
    bf16_t* Wcb  = wsb + 802816;
    bf16_t* Wd1t = wsb + 819200;
    bf16_t* Wd2t = wsb + 851968;
    bf16_t* Wd3t = wsb + 1114112;
    bf16_t* zbuf = wsb + 1376256;   // (B,256) bf16
    bf16_t* zcb  = wsb + 9764864;   // (B,64)  bf16

    cast_kernel<<<dim3(5376), dim3(256), 0, stream>>>(
        W1, W2, muW, lvW, Wqkv, Wo, Wc, Wd1, Wd2, Wd3, wsb);
    enc_kernel<<<dim3(512), dim3(512), 0, stream>>>(
        x, eps, W1t, b1, W2t, b2, Ht, mub, lvb, zbuf);
    attn_kernel<<<dim3(512), dim3(512), 0, stream>>>(
        zbuf, Wqkvb, bqkv, Wob, bo, Wcb, bc, zcb);
    dec_kernel<<<dim3(2560), dim3(512), 0, stream>>>(
        zbuf, zcb, Wd1t, bd1, Wd2t, bd2, Wd3t, bd3, out);
}